// Round 1
// baseline (174.512 us; speedup 1.0000x reference)
//
#include <hip/hip_runtime.h>

// HolographicConv: out = Re(ifft2(fft2(x) * W)), B == C_out == 16 -> pure
// elementwise complex multiply in frequency space per (b,c) image slice.
// 256 images of 256x256 complex64.
//
// K1: row FFT (forward)          x (f32 re,im) -> ws (float2)
// K2: col FFT + mul W + col IFFT ws -> ws        (LDS tile transpose)
// K3: row IFFT, write real/65536 ws -> out (f32)
//
// FFT-256 = radix-4 Stockham, 4 stages, one wave per transform,
// 4 complex elems/lane (v[r] = elem(lane + 64*r) at EVERY stage boundary).

#define PI_F 3.14159265358979323846f

__device__ __forceinline__ float2 cadd(float2 a, float2 b){ return make_float2(a.x+b.x, a.y+b.y); }
__device__ __forceinline__ float2 csub(float2 a, float2 b){ return make_float2(a.x-b.x, a.y-b.y); }
__device__ __forceinline__ float2 cmul(float2 a, float2 b){
  return make_float2(a.x*b.x - a.y*b.y, a.x*b.y + a.y*b.x);
}

// XOR swizzle: every stage's scatter/ gather lands 4 lanes per bank-pair
// (same density as unit-stride b64) -> effectively conflict-free.
__device__ __forceinline__ int SW(int e){ return e ^ (e >> 4); }

template<int DIR>  // +1: forward e^{-i}, -1: inverse e^{+i} (unnormalized)
__device__ __forceinline__ void bfly4(float2& a, float2& b, float2& c, float2& d,
                                      float2 w1, float2 w2, float2 w3)
{
  float2 apc = cadd(a,c), amc = csub(a,c);
  float2 bpd = cadd(b,d), bmd = csub(b,d);
  float2 jb = (DIR > 0) ? make_float2(-bmd.y, bmd.x)   //  i*(b-d)
                        : make_float2( bmd.y,-bmd.x);  // -i*(b-d)
  a = cadd(apc, bpd);
  b = cmul(w1, csub(amc, jb));
  c = cmul(w2, csub(apc, bpd));
  d = cmul(w3, cadd(amc, jb));
}

// tw[k] = exp(-2*pi*i*k/256). scr = per-wave 256-entry float2 scratch.
template<int DIR>
__device__ __forceinline__ void fft256(float2 v[4], float2* scr, const float2* tw, int lane)
{
  #pragma unroll
  for (int st = 0; st < 3; ++st) {               // s = 1, 4, 16
    const int s  = 1 << (2*st);
    const int ps = lane & ~(s-1);                // p*s
    const int q  = lane &  (s-1);
    float2 w1 = tw[ps];
    float2 w2 = tw[(2*ps) & 255];
    float2 w3 = tw[(3*ps) & 255];
    if (DIR < 0) { w1.y = -w1.y; w2.y = -w2.y; w3.y = -w3.y; }
    bfly4<DIR>(v[0], v[1], v[2], v[3], w1, w2, w3);
    const int dbase = q + 4*ps;                  // q + s*4p
    __builtin_amdgcn_wave_barrier();
    scr[SW(dbase + 0*s)] = v[0];
    scr[SW(dbase + 1*s)] = v[1];
    scr[SW(dbase + 2*s)] = v[2];
    scr[SW(dbase + 3*s)] = v[3];
    __builtin_amdgcn_wave_barrier();             // in-order LDS per wave -> safe
    v[0] = scr[SW(lane +   0)];
    v[1] = scr[SW(lane +  64)];
    v[2] = scr[SW(lane + 128)];
    v[3] = scr[SW(lane + 192)];
    __builtin_amdgcn_wave_barrier();
  }
  // final stage: s=64, p=0 -> twiddles = 1, dest == own regs
  const float2 one = make_float2(1.f, 0.f);
  bfly4<DIR>(v[0], v[1], v[2], v[3], one, one, one);
}

__device__ __forceinline__ void init_tw(float2* tw, int tid)
{
  float sv, cv;
  sincosf(-2.0f * PI_F * (float)tid / 256.0f, &sv, &cv);
  tw[tid] = make_float2(cv, sv);
}

// ---------------- K1: row forward FFT --------------------------------------
__global__ __launch_bounds__(256) void k_rowfft(const float* __restrict__ xr,
                                                const float* __restrict__ xi,
                                                float2* __restrict__ ws)
{
  __shared__ float2 tw[256];
  __shared__ float2 scr[4][256];
  const int tid = threadIdx.x;
  init_tw(tw, tid);
  __syncthreads();
  const int wave = tid >> 6, lane = tid & 63;
  const long long row = (long long)blockIdx.x * 4 + wave;
  const float* pr = xr + row * 256;
  const float* pi = xi + row * 256;
  float2 v[4];
  #pragma unroll
  for (int r = 0; r < 4; ++r)
    v[r] = make_float2(pr[lane + 64*r], pi[lane + 64*r]);
  fft256<1>(v, scr[wave], tw, lane);
  float2* o = ws + row * 256;
  #pragma unroll
  for (int r = 0; r < 4; ++r) o[lane + 64*r] = v[r];
}

// ---------------- K2: column FFT * W, column IFFT --------------------------
// block = 256 thr, handles 16 columns of one image. LDS ~78 KiB -> 2 blk/CU.
__global__ __launch_bounds__(256) void k_colpass(float2* __restrict__ ws,
                                                 const float* __restrict__ wr,
                                                 const float* __restrict__ wi,
                                                 int img0)
{
  __shared__ float2 xt[256][17];   // padded: col reads 4 lanes/bank-pair
  __shared__ float2 wt[256][17];
  __shared__ float2 scr[4][256];
  __shared__ float2 tw[256];
  const int tid = threadIdx.x;
  init_tw(tw, tid);
  const int imgl = blockIdx.x >> 4;
  const int w0   = (blockIdx.x & 15) * 16;
  const size_t base_l = (size_t)imgl * 65536 + w0;                 // ws (chunk-local)
  const size_t base_g = (size_t)(img0 + imgl) * 65536 + w0;        // W (absolute)
  const int c  = tid & 15;
  const int h0 = tid >> 4;
  #pragma unroll
  for (int t = 0; t < 16; ++t) {
    const int h = h0 + t*16;
    xt[h][c] = ws[base_l + (size_t)h*256 + c];
    wt[h][c] = make_float2(wr[base_g + (size_t)h*256 + c],
                           wi[base_g + (size_t)h*256 + c]);
  }
  __syncthreads();
  const int wave = tid >> 6, lane = tid & 63;
  #pragma unroll 1
  for (int cc = 0; cc < 4; ++cc) {
    const int col = wave * 4 + cc;
    float2 v[4];
    #pragma unroll
    for (int r = 0; r < 4; ++r) v[r] = xt[lane + 64*r][col];
    fft256<1>(v, scr[wave], tw, lane);
    #pragma unroll
    for (int r = 0; r < 4; ++r) v[r] = cmul(v[r], wt[lane + 64*r][col]);
    fft256<-1>(v, scr[wave], tw, lane);
    #pragma unroll
    for (int r = 0; r < 4; ++r) xt[lane + 64*r][col] = v[r];
  }
  __syncthreads();
  #pragma unroll
  for (int t = 0; t < 16; ++t) {
    const int h = h0 + t*16;
    ws[base_l + (size_t)h*256 + c] = xt[h][c];
  }
}

// ---------------- K3: row inverse FFT, write Re/65536 ----------------------
__global__ __launch_bounds__(256) void k_rowifft(const float2* __restrict__ ws,
                                                 float* __restrict__ out)
{
  __shared__ float2 tw[256];
  __shared__ float2 scr[4][256];
  const int tid = threadIdx.x;
  init_tw(tw, tid);
  __syncthreads();
  const int wave = tid >> 6, lane = tid & 63;
  const long long row = (long long)blockIdx.x * 4 + wave;
  const float2* p = ws + row * 256;
  float2 v[4];
  #pragma unroll
  for (int r = 0; r < 4; ++r) v[r] = p[lane + 64*r];
  fft256<-1>(v, scr[wave], tw, lane);
  float* o = out + row * 256;
  const float sc = 1.0f / 65536.0f;  // 1/(H*W) ifft2 normalization
  #pragma unroll
  for (int r = 0; r < 4; ++r) o[lane + 64*r] = v[r].x * sc;
}

extern "C" void kernel_launch(void* const* d_in, const int* in_sizes, int n_in,
                              void* d_out, int out_size, void* d_ws, size_t ws_size,
                              hipStream_t stream)
{
  const float* xr = (const float*)d_in[0];
  const float* xi = (const float*)d_in[1];
  const float* wr = (const float*)d_in[2];
  const float* wi = (const float*)d_in[3];
  float* out = (float*)d_out;

  const int IMG = 256;                               // B * C_IN
  const size_t per_img = (size_t)65536 * sizeof(float2);  // 512 KiB
  int ipc = (int)(ws_size / per_img);                // images per chunk
  if (ipc < 1)  ipc = 1;
  if (ipc > IMG) ipc = IMG;
  float2* wsp = (float2*)d_ws;

  for (int img0 = 0; img0 < IMG; img0 += ipc) {
    const int n = (IMG - img0 < ipc) ? (IMG - img0) : ipc;
    k_rowfft <<<dim3(n*64), dim3(256), 0, stream>>>(xr + (size_t)img0*65536,
                                                    xi + (size_t)img0*65536, wsp);
    k_colpass<<<dim3(n*16), dim3(256), 0, stream>>>(wsp, wr, wi, img0);
    k_rowifft<<<dim3(n*64), dim3(256), 0, stream>>>(wsp, out + (size_t)img0*65536);
  }
}